// Round 6
// baseline (699.076 us; speedup 1.0000x reference)
//
#include <hip/hip_runtime.h>
#include <math.h>

// GCN 3-layer + classifier — 2-D binned (dst-range x src-range) counting sort
// + LDS-atomic bucket aggregation with L1-resident gather windows.
//
// Round-6 theory: round-5 showed bagg kernels pinned at ~13 cyc per divergent
// gather lane regardless of occupancy -> per-CU L1-miss (MSHR) throughput
// bound. Fix: order edges so consecutive edges gather from a 16KB src window
// (1024 nodes x float4) -> ~64% L1 hits.
//
// Fast path:
//  pass1: bin edges by dst-range (49 bins of 4096) -> packed (src<<12|local)
//  pass2: within each dst-bin, bin by src-bucket (1024 nodes, <=196 buckets)
//  bdeg : per (bin,slice) LDS degree hist -> partials -> mergedeg -> dinv
//  linear1: g1 = dinv*(x@W1)
//  bagg4 (x2): per (bin,slice): LDS acc (64KB, XOR-swizzled), stream buckets,
//              gather gin[src] (L1-windowed), ds_add; write partial slice
//  merge44/42: sum partials + self term, tanh, next linear
//  bagg2/merge2out: same with 2-wide features, final classifier write
//
// Math identity: agg[d] = dinv[d]*( g[d] + sum_{in} g[s] ),  g = dinv*h.

#define RBITS 12
#define RNGD  (1 << RBITS)       // 4096 dst nodes per bin
#define NRD_MAX 49
#define SBITS 10
#define SW    (1 << SBITS)       // 1024 src nodes per bucket (16KB window)
#define NS_MAX 200
#define CAP1  133120             // edges per dst bin (mean 131072 + 5.7 sigma)
#define CAP2  896                // edges per (dst,src) bucket (mean 671 + 8.7 sigma)
#define SL    10                 // aggregation slices per dst bin
#define PB    1024
#define EPT1  8
#define EPB1  (PB * EPT1)        // 8192 edges per pass1 block
#define P2BUF 8448               // >= ceil(CAP1/16)

// ---------------- cursors ----------------

__global__ void k_initcur2d(int* __restrict__ c1, int* __restrict__ c2) {
    int t = blockIdx.x * blockDim.x + threadIdx.x;
    if (t < NRD_MAX) c1[t * 16] = t * CAP1;
    if (t < NRD_MAX * NS_MAX) c2[t * 16] = t * CAP2;
}

// ---------------- pass1: bin by dst-range ----------------

__global__ __launch_bounds__(PB) void k_pass1(const int* __restrict__ src,
                                              const int* __restrict__ dst,
                                              int* __restrict__ c1,
                                              int* __restrict__ buf1, int e, int nrd) {
    __shared__ int hist[NRD_MAX];
    __shared__ int start[NRD_MAX + 1];
    __shared__ int gbase[NRD_MAX];
    __shared__ int cur[NRD_MAX];
    __shared__ int buf[EPB1];
    int t = threadIdx.x;
    if (t < NRD_MAX) hist[t] = 0;
    __syncthreads();

    int ds[EPT1], sr[EPT1];
    int base = blockIdx.x * EPB1;
#pragma unroll
    for (int k = 0; k < 2; k++) {
        int idx = base + (k * PB + t) * 4;
        if (idx + 3 < e) {
            int4 d4 = *(const int4*)(dst + idx);
            int4 s4 = *(const int4*)(src + idx);
            ds[4*k+0] = d4.x; ds[4*k+1] = d4.y; ds[4*k+2] = d4.z; ds[4*k+3] = d4.w;
            sr[4*k+0] = s4.x; sr[4*k+1] = s4.y; sr[4*k+2] = s4.z; sr[4*k+3] = s4.w;
        } else {
#pragma unroll
            for (int j = 0; j < 4; j++) {
                int i2 = idx + j;
                if (i2 < e) { ds[4*k+j] = dst[i2]; sr[4*k+j] = src[i2]; }
                else ds[4*k+j] = -1;
            }
        }
    }
#pragma unroll
    for (int k = 0; k < EPT1; k++)
        if (ds[k] >= 0) atomicAdd(&hist[ds[k] >> RBITS], 1);
    __syncthreads();

    if (t == 0) {
        int run = 0;
        for (int i = 0; i < nrd; i++) { start[i] = run; run += hist[i]; }
        start[nrd] = run;
    }
    __syncthreads();
    if (t < nrd) {
        cur[t] = start[t];
        gbase[t] = hist[t] ? atomicAdd(&c1[t * 16], hist[t]) : 0;
    }
    __syncthreads();

#pragma unroll
    for (int k = 0; k < EPT1; k++) {
        if (ds[k] >= 0) {
            int bin = ds[k] >> RBITS;
            int p = atomicAdd(&cur[bin], 1);
            buf[p] = (sr[k] << RBITS) | (ds[k] & (RNGD - 1));
        }
    }
    __syncthreads();

    int total = start[nrd];
    for (int j = t; j < total; j += PB) {
        int lo = 0, hi = nrd;
        while (hi - lo > 1) { int mid = (lo + hi) >> 1; if (start[mid] <= j) lo = mid; else hi = mid; }
        int g = gbase[lo] + (j - start[lo]);
        if (g < (lo + 1) * CAP1) buf1[g] = buf[j];
    }
}

// ---------------- pass2: bin each dst-bin by src-bucket ----------------

__global__ __launch_bounds__(PB) void k_pass2(const int* __restrict__ buf1,
                                              const int* __restrict__ c1,
                                              int* __restrict__ c2,
                                              int* __restrict__ csrp, int ns) {
    __shared__ int hist[NS_MAX];
    __shared__ int start[NS_MAX + 1];
    __shared__ int gbase[NS_MAX];
    __shared__ int cur[NS_MAX];
    __shared__ int buf[P2BUF];
    int t = threadIdx.x;
    int bin = blockIdx.x >> 4, chunk = blockIdx.x & 15;
    int cnt = c1[bin * 16] - bin * CAP1; if (cnt > CAP1) cnt = CAP1;
    int csz = (cnt + 15) >> 4;
    int lo = chunk * csz;
    int hi = lo + csz; if (hi > cnt) hi = cnt;
    int m = hi - lo; if (m < 0) m = 0;
    const int* ebase = buf1 + (size_t)bin * CAP1 + lo;

    for (int i = t; i < NS_MAX; i += PB) hist[i] = 0;
    __syncthreads();

    int pv[9];
#pragma unroll
    for (int k = 0; k < 9; k++) {
        int j = t + k * PB;
        if (j < m) {
            pv[k] = __builtin_nontemporal_load(ebase + j);
            atomicAdd(&hist[pv[k] >> (RBITS + SBITS)], 1);
        }
    }
    __syncthreads();

    if (t == 0) {
        int run = 0;
        for (int i = 0; i < ns; i++) { start[i] = run; run += hist[i]; }
        start[ns] = run;
    }
    __syncthreads();
    if (t < ns) {
        cur[t] = start[t];
        gbase[t] = hist[t] ? atomicAdd(&c2[(bin * NS_MAX + t) * 16], hist[t]) : 0;
    }
    __syncthreads();

#pragma unroll
    for (int k = 0; k < 9; k++) {
        int j = t + k * PB;
        if (j < m) {
            int s = pv[k] >> (RBITS + SBITS);
            int p = atomicAdd(&cur[s], 1);
            buf[p] = pv[k];
        }
    }
    __syncthreads();

    int total = start[ns];
    for (int j = t; j < total; j += PB) {
        int l = 0, h = ns;
        while (h - l > 1) { int mid = (l + h) >> 1; if (start[mid] <= j) l = mid; else h = mid; }
        int g = gbase[l] + (j - start[l]);
        if (g < (bin * NS_MAX + l) * CAP2 + CAP2) csrp[g] = buf[j];
    }
}

// ---------------- degree (sliced) ----------------

__global__ __launch_bounds__(PB) void k_bdeg2(const int* __restrict__ csrp,
                                              const int* __restrict__ c2,
                                              int* __restrict__ pdeg, int ns) {
    __shared__ int deg[RNGD];
    int t = threadIdx.x;
    int bin = blockIdx.x / SL, sl = blockIdx.x % SL;
    for (int i = t; i < RNGD; i += PB) deg[i] = 0;
    __syncthreads();
    int spb = (ns + SL - 1) / SL;
    int s0 = sl * spb, s1 = s0 + spb; if (s1 > ns) s1 = ns;
    for (int s = s0; s < s1; s++) {
        int b2 = (bin * NS_MAX + s) * CAP2;
        int e2 = c2[(bin * NS_MAX + s) * 16]; if (e2 > b2 + CAP2) e2 = b2 + CAP2;
        for (int j = b2 + t; j < e2; j += PB)
            atomicAdd(&deg[__builtin_nontemporal_load(csrp + j) & (RNGD - 1)], 1);
    }
    __syncthreads();
    int* out = pdeg + (size_t)blockIdx.x * RNGD;
    for (int i = t; i < RNGD; i += PB) out[i] = deg[i];
}

__global__ void k_mergedeg(const int* __restrict__ pdeg, float* __restrict__ dinv, int n) {
    int i = blockIdx.x * blockDim.x + threadIdx.x;
    if (i >= n) return;
    int bin = i >> RBITS, local = i & (RNGD - 1);
    const int* p = pdeg + (size_t)bin * SL * RNGD + local;
    int s = 0;
#pragma unroll
    for (int k = 0; k < SL; k++) s += p[(size_t)k * RNGD];
    dinv[i] = rsqrtf(1.0f + (float)s);
}

// ---------------- layer 1 linear: g1 = dinv * (x @ W1), wave-per-row ----------------

__global__ void k_linear1(const float* __restrict__ x, const float* __restrict__ W1,
                          const float* __restrict__ dinv, float4* __restrict__ g1, int n) {
    int lane = threadIdx.x & 63;
    int wave = blockIdx.x * (blockDim.x >> 6) + (threadIdx.x >> 6);
    int nwaves = gridDim.x * (blockDim.x >> 6);
    float4 w0 = ((const float4*)W1)[2 * lane];
    float4 w1 = ((const float4*)W1)[2 * lane + 1];
    for (int row = wave; row < n; row += nwaves) {
        float2 xv = ((const float2*)(x + (size_t)row * 128))[lane];
        float p0 = xv.x * w0.x + xv.y * w1.x;
        float p1 = xv.x * w0.y + xv.y * w1.y;
        float p2 = xv.x * w0.z + xv.y * w1.z;
        float p3 = xv.x * w0.w + xv.y * w1.w;
#pragma unroll
        for (int off = 32; off; off >>= 1) {
            p0 += __shfl_xor(p0, off, 64);
            p1 += __shfl_xor(p1, off, 64);
            p2 += __shfl_xor(p2, off, 64);
            p3 += __shfl_xor(p3, off, 64);
        }
        if (lane == 0) {
            float dv = dinv[row];
            g1[row] = make_float4(dv * p0, dv * p1, dv * p2, dv * p3);
        }
    }
}

// ---------------- bucketed aggregation (L1-windowed gathers) ----------------

__global__ __launch_bounds__(PB) void k_bagg4(const int* __restrict__ csrp,
                                              const int* __restrict__ c2,
                                              const float4* __restrict__ gin,
                                              float* __restrict__ partial, int ns) {
    __shared__ float acc[RNGD * 4];   // 64KB, XOR-swizzled: idx = local*4 + (k ^ ((local>>3)&3))
    int t = threadIdx.x;
    int bin = blockIdx.x / SL, sl = blockIdx.x % SL;
    for (int i = t; i < RNGD * 4; i += PB) acc[i] = 0.0f;
    __syncthreads();
    int spb = (ns + SL - 1) / SL;
    int s0 = sl * spb, s1 = s0 + spb; if (s1 > ns) s1 = ns;
    for (int s = s0; s < s1; s++) {
        int b2 = (bin * NS_MAX + s) * CAP2;
        int e2 = c2[(bin * NS_MAX + s) * 16]; if (e2 > b2 + CAP2) e2 = b2 + CAP2;
        for (int j = b2 + t; j < e2; j += PB) {
            int p = __builtin_nontemporal_load(csrp + j);
            int local = p & (RNGD - 1);
            float4 g = gin[p >> RBITS];
            int sw = (local >> 3) & 3;
            atomicAdd(&acc[local * 4 + (0 ^ sw)], g.x);
            atomicAdd(&acc[local * 4 + (1 ^ sw)], g.y);
            atomicAdd(&acc[local * 4 + (2 ^ sw)], g.z);
            atomicAdd(&acc[local * 4 + (3 ^ sw)], g.w);
        }
    }
    __syncthreads();
    float* out = partial + (size_t)blockIdx.x * (RNGD * 4);
    for (int i = t; i < RNGD * 4; i += PB) out[i] = acc[i];
}

__global__ __launch_bounds__(PB) void k_bagg2(const int* __restrict__ csrp,
                                              const int* __restrict__ c2,
                                              const float2* __restrict__ gin,
                                              float* __restrict__ partial, int ns) {
    __shared__ float acc[RNGD * 2];   // 32KB, idx = local*2 + (k ^ ((local>>4)&1))
    int t = threadIdx.x;
    int bin = blockIdx.x / SL, sl = blockIdx.x % SL;
    for (int i = t; i < RNGD * 2; i += PB) acc[i] = 0.0f;
    __syncthreads();
    int spb = (ns + SL - 1) / SL;
    int s0 = sl * spb, s1 = s0 + spb; if (s1 > ns) s1 = ns;
    for (int s = s0; s < s1; s++) {
        int b2 = (bin * NS_MAX + s) * CAP2;
        int e2 = c2[(bin * NS_MAX + s) * 16]; if (e2 > b2 + CAP2) e2 = b2 + CAP2;
        for (int j = b2 + t; j < e2; j += PB) {
            int p = __builtin_nontemporal_load(csrp + j);
            int local = p & (RNGD - 1);
            float2 g = gin[p >> RBITS];
            int sw = (local >> 4) & 1;
            atomicAdd(&acc[local * 2 + (0 ^ sw)], g.x);
            atomicAdd(&acc[local * 2 + (1 ^ sw)], g.y);
        }
    }
    __syncthreads();
    float* out = partial + (size_t)blockIdx.x * (RNGD * 2);
    for (int i = t; i < RNGD * 2; i += PB) out[i] = acc[i];
}

// ---------------- merges (partial-sum + self term + tanh + next linear) ----------------

__global__ void k_merge44(const float* __restrict__ partial, const float4* __restrict__ gin,
                          const float* __restrict__ dinv, float4* __restrict__ gout,
                          const float* __restrict__ W, const float* __restrict__ bv, int n) {
    int i = blockIdx.x * blockDim.x + threadIdx.x;
    if (i >= n) return;
    int bin = i >> RBITS, local = i & (RNGD - 1);
    const float4* p = (const float4*)partial + (size_t)bin * SL * RNGD + local;
    float a[4] = {0.f, 0.f, 0.f, 0.f};
#pragma unroll
    for (int k = 0; k < SL; k++) {
        float4 v = p[(size_t)k * RNGD];
        a[0] += v.x; a[1] += v.y; a[2] += v.z; a[3] += v.w;
    }
    int sw = (local >> 3) & 3;
    float f0 = a[0 ^ sw], f1 = a[1 ^ sw], f2 = a[2 ^ sw], f3 = a[3 ^ sw];
    float4 gs = gin[i];
    float dv = dinv[i];
    float t0 = tanhf(dv * (gs.x + f0) + bv[0]);
    float t1 = tanhf(dv * (gs.y + f1) + bv[1]);
    float t2 = tanhf(dv * (gs.z + f2) + bv[2]);
    float t3 = tanhf(dv * (gs.w + f3) + bv[3]);
    float4 o;
    o.x = dv * (t0 * W[0] + t1 * W[4] + t2 * W[8]  + t3 * W[12]);
    o.y = dv * (t0 * W[1] + t1 * W[5] + t2 * W[9]  + t3 * W[13]);
    o.z = dv * (t0 * W[2] + t1 * W[6] + t2 * W[10] + t3 * W[14]);
    o.w = dv * (t0 * W[3] + t1 * W[7] + t2 * W[11] + t3 * W[15]);
    gout[i] = o;
}

__global__ void k_merge42(const float* __restrict__ partial, const float4* __restrict__ gin,
                          const float* __restrict__ dinv, float2* __restrict__ gout,
                          const float* __restrict__ W, const float* __restrict__ bv, int n) {
    int i = blockIdx.x * blockDim.x + threadIdx.x;
    if (i >= n) return;
    int bin = i >> RBITS, local = i & (RNGD - 1);
    const float4* p = (const float4*)partial + (size_t)bin * SL * RNGD + local;
    float a[4] = {0.f, 0.f, 0.f, 0.f};
#pragma unroll
    for (int k = 0; k < SL; k++) {
        float4 v = p[(size_t)k * RNGD];
        a[0] += v.x; a[1] += v.y; a[2] += v.z; a[3] += v.w;
    }
    int sw = (local >> 3) & 3;
    float f0 = a[0 ^ sw], f1 = a[1 ^ sw], f2 = a[2 ^ sw], f3 = a[3 ^ sw];
    float4 gs = gin[i];
    float dv = dinv[i];
    float t0 = tanhf(dv * (gs.x + f0) + bv[0]);
    float t1 = tanhf(dv * (gs.y + f1) + bv[1]);
    float t2 = tanhf(dv * (gs.z + f2) + bv[2]);
    float t3 = tanhf(dv * (gs.w + f3) + bv[3]);
    float h0 = t0 * W[0] + t1 * W[2] + t2 * W[4] + t3 * W[6];
    float h1 = t0 * W[1] + t1 * W[3] + t2 * W[5] + t3 * W[7];
    gout[i] = make_float2(dv * h0, dv * h1);
}

__global__ void k_merge2out(const float* __restrict__ partial, const float2* __restrict__ gin,
                            const float* __restrict__ dinv, const float* __restrict__ b3,
                            const float* __restrict__ Wc, const float* __restrict__ bc,
                            float* __restrict__ out, float2* __restrict__ hout, int n) {
    int i = blockIdx.x * blockDim.x + threadIdx.x;
    if (i >= n) return;
    int bin = i >> RBITS, local = i & (RNGD - 1);
    const float2* p = (const float2*)partial + (size_t)bin * SL * RNGD + local;
    float a[2] = {0.f, 0.f};
#pragma unroll
    for (int k = 0; k < SL; k++) {
        float2 v = p[(size_t)k * RNGD];
        a[0] += v.x; a[1] += v.y;
    }
    int sw = (local >> 4) & 1;
    float f0 = a[0 ^ sw], f1 = a[1 ^ sw];
    float2 gs = gin[i];
    float dv = dinv[i];
    float t0 = tanhf(dv * (gs.x + f0) + b3[0]);
    float t1 = tanhf(dv * (gs.y + f1) + b3[1]);
    hout[i] = make_float2(t0, t1);
    float4* o = (float4*)(out + (size_t)i * 16);
#pragma unroll
    for (int q = 0; q < 4; q++) {
        float4 v;
        v.x = t0 * Wc[4*q+0] + t1 * Wc[16+4*q+0] + bc[4*q+0];
        v.y = t0 * Wc[4*q+1] + t1 * Wc[16+4*q+1] + bc[4*q+1];
        v.z = t0 * Wc[4*q+2] + t1 * Wc[16+4*q+2] + bc[4*q+2];
        v.w = t0 * Wc[4*q+3] + t1 * Wc[16+4*q+3] + bc[4*q+3];
        o[q] = v;
    }
}

// ---------------- fallback path: round-5 proven 1-D bucketed version ----------------

#define FNR 500
#define FRNG 400
#define FCAP 16384
#define FHB 1024
#define FEPT 8
#define FEPB (FHB * FEPT)
#define FAB 1024

__global__ void kf_initcur(int* __restrict__ cursor) {
    int t = blockIdx.x * blockDim.x + threadIdx.x;
    if (t < FNR) cursor[t * 16] = t * FCAP;
}

__global__ __launch_bounds__(FHB) void kf_build(const int* __restrict__ src,
                                                const int* __restrict__ dst,
                                                int* __restrict__ cursor,
                                                int* __restrict__ csrp, int e) {
    __shared__ int hist[FNR];
    __shared__ int scn[FHB];
    __shared__ int start[FNR + 1];
    __shared__ int gbase[FNR];
    __shared__ int cur[FNR];
    __shared__ int buf[FEPB];
    int t = threadIdx.x;
    for (int i = t; i < FNR; i += FHB) hist[i] = 0;
    __syncthreads();
    int ds[FEPT], sr[FEPT];
    int base = blockIdx.x * FEPB;
#pragma unroll
    for (int k = 0; k < 2; k++) {
        int idx = base + k * FHB * 4 + t * 4;
        if (idx + 3 < e) {
            int4 d4 = *(const int4*)(dst + idx);
            int4 s4 = *(const int4*)(src + idx);
            ds[4*k+0]=d4.x; ds[4*k+1]=d4.y; ds[4*k+2]=d4.z; ds[4*k+3]=d4.w;
            sr[4*k+0]=s4.x; sr[4*k+1]=s4.y; sr[4*k+2]=s4.z; sr[4*k+3]=s4.w;
        } else {
#pragma unroll
            for (int j = 0; j < 4; j++) {
                int i2 = idx + j;
                if (i2 < e) { ds[4*k+j] = dst[i2]; sr[4*k+j] = src[i2]; }
                else ds[4*k+j] = -1;
            }
        }
    }
#pragma unroll
    for (int k = 0; k < FEPT; k++)
        if (ds[k] >= 0) atomicAdd(&hist[ds[k] / FRNG], 1);
    __syncthreads();
    scn[t] = (t < FNR) ? hist[t] : 0;
    __syncthreads();
    for (int off = 1; off < FHB; off <<= 1) {
        int add = (t >= off) ? scn[t - off] : 0;
        __syncthreads();
        scn[t] += add;
        __syncthreads();
    }
    if (t < FNR) {
        int c = hist[t];
        int st = scn[t] - c;
        start[t] = st; cur[t] = st;
        gbase[t] = c ? atomicAdd(&cursor[t * 16], c) : 0;
    }
    if (t == 0) start[FNR] = scn[FNR - 1];
    __syncthreads();
#pragma unroll
    for (int k = 0; k < FEPT; k++) {
        if (ds[k] >= 0) {
            int bin = ds[k] / FRNG;
            int p = atomicAdd(&cur[bin], 1);
            buf[p] = (sr[k] << 9) | (ds[k] - bin * FRNG);
        }
    }
    __syncthreads();
    int total = start[FNR];
    for (int j = t; j < total; j += FHB) {
        int lo = 0, hi = FNR;
        while (hi - lo > 1) { int mid = (lo + hi) >> 1; if (start[mid] <= j) lo = mid; else hi = mid; }
        int g = gbase[lo] + (j - start[lo]);
        if (g < (lo + 1) * FCAP) csrp[g] = buf[j];
    }
}

__global__ __launch_bounds__(FAB) void kf_bdeg(const int* __restrict__ csrp,
                                               const int* __restrict__ cursor,
                                               float* __restrict__ dinv, int n) {
    __shared__ int deg[FRNG];
    int t = threadIdx.x, b = blockIdx.x;
    for (int i = t; i < FRNG; i += FAB) deg[i] = 0;
    __syncthreads();
    int s0 = b * FCAP;
    int s1 = cursor[b * 16]; if (s1 > s0 + FCAP) s1 = s0 + FCAP;
    int cnt = s1 - s0;
    const int4* cp = (const int4*)(csrp + s0);
    int ng = cnt >> 2;
    for (int g = t; g < ng; g += FAB) {
        int4 p = cp[g];
        atomicAdd(&deg[p.x & 511], 1);
        atomicAdd(&deg[p.y & 511], 1);
        atomicAdd(&deg[p.z & 511], 1);
        atomicAdd(&deg[p.w & 511], 1);
    }
    int rem = s0 + (ng << 2) + t;
    if (rem < s1) atomicAdd(&deg[csrp[rem] & 511], 1);
    __syncthreads();
    int basen = b * FRNG;
    for (int i = t; i < FRNG; i += FAB) {
        int node = basen + i;
        if (node < n) dinv[node] = rsqrtf(1.0f + (float)deg[i]);
    }
}

__device__ __forceinline__ void facc4(float* acc, int p, const float4* __restrict__ gin) {
    int local = p & 511;
    float4 g = gin[p >> 9];
    atomicAdd(&acc[local * 5 + 0], g.x);
    atomicAdd(&acc[local * 5 + 1], g.y);
    atomicAdd(&acc[local * 5 + 2], g.z);
    atomicAdd(&acc[local * 5 + 3], g.w);
}

__global__ __launch_bounds__(FAB) void kf_bagg44(const int* __restrict__ csrp,
                                                 const int* __restrict__ cursor,
                                                 const float* __restrict__ dinv,
                                                 const float4* __restrict__ gin,
                                                 float4* __restrict__ gout,
                                                 const float* __restrict__ W,
                                                 const float* __restrict__ bv, int n) {
    __shared__ float acc[FRNG * 5];
    int t = threadIdx.x, b = blockIdx.x;
    for (int i = t; i < FRNG * 5; i += FAB) acc[i] = 0.0f;
    __syncthreads();
    int s0 = b * FCAP;
    int s1 = cursor[b * 16]; if (s1 > s0 + FCAP) s1 = s0 + FCAP;
    int cnt = s1 - s0;
    const int4* cp = (const int4*)(csrp + s0);
    int ng = cnt >> 2;
    for (int g = t; g < ng; g += FAB) {
        int4 p = cp[g];
        facc4(acc, p.x, gin); facc4(acc, p.y, gin);
        facc4(acc, p.z, gin); facc4(acc, p.w, gin);
    }
    int rem = s0 + (ng << 2) + t;
    if (rem < s1) facc4(acc, csrp[rem], gin);
    __syncthreads();
    int basen = b * FRNG;
    for (int i = t; i < FRNG; i += FAB) {
        int node = basen + i;
        if (node >= n) continue;
        float4 gs = gin[node];
        float dv = dinv[node];
        float t0 = tanhf(dv * (gs.x + acc[i*5+0]) + bv[0]);
        float t1 = tanhf(dv * (gs.y + acc[i*5+1]) + bv[1]);
        float t2 = tanhf(dv * (gs.z + acc[i*5+2]) + bv[2]);
        float t3 = tanhf(dv * (gs.w + acc[i*5+3]) + bv[3]);
        float4 o;
        o.x = dv * (t0*W[0] + t1*W[4] + t2*W[8]  + t3*W[12]);
        o.y = dv * (t0*W[1] + t1*W[5] + t2*W[9]  + t3*W[13]);
        o.z = dv * (t0*W[2] + t1*W[6] + t2*W[10] + t3*W[14]);
        o.w = dv * (t0*W[3] + t1*W[7] + t2*W[11] + t3*W[15]);
        gout[node] = o;
    }
}

__global__ __launch_bounds__(FAB) void kf_bagg42(const int* __restrict__ csrp,
                                                 const int* __restrict__ cursor,
                                                 const float* __restrict__ dinv,
                                                 const float4* __restrict__ gin,
                                                 float2* __restrict__ gout,
                                                 const float* __restrict__ W,
                                                 const float* __restrict__ bv, int n) {
    __shared__ float acc[FRNG * 5];
    int t = threadIdx.x, b = blockIdx.x;
    for (int i = t; i < FRNG * 5; i += FAB) acc[i] = 0.0f;
    __syncthreads();
    int s0 = b * FCAP;
    int s1 = cursor[b * 16]; if (s1 > s0 + FCAP) s1 = s0 + FCAP;
    int cnt = s1 - s0;
    const int4* cp = (const int4*)(csrp + s0);
    int ng = cnt >> 2;
    for (int g = t; g < ng; g += FAB) {
        int4 p = cp[g];
        facc4(acc, p.x, gin); facc4(acc, p.y, gin);
        facc4(acc, p.z, gin); facc4(acc, p.w, gin);
    }
    int rem = s0 + (ng << 2) + t;
    if (rem < s1) facc4(acc, csrp[rem], gin);
    __syncthreads();
    int basen = b * FRNG;
    for (int i = t; i < FRNG; i += FAB) {
        int node = basen + i;
        if (node >= n) continue;
        float4 gs = gin[node];
        float dv = dinv[node];
        float t0 = tanhf(dv * (gs.x + acc[i*5+0]) + bv[0]);
        float t1 = tanhf(dv * (gs.y + acc[i*5+1]) + bv[1]);
        float t2 = tanhf(dv * (gs.z + acc[i*5+2]) + bv[2]);
        float t3 = tanhf(dv * (gs.w + acc[i*5+3]) + bv[3]);
        float h0 = t0*W[0] + t1*W[2] + t2*W[4] + t3*W[6];
        float h1 = t0*W[1] + t1*W[3] + t2*W[5] + t3*W[7];
        gout[node] = make_float2(dv * h0, dv * h1);
    }
}

__global__ __launch_bounds__(FAB) void kf_bagg2out(const int* __restrict__ csrp,
                                                   const int* __restrict__ cursor,
                                                   const float* __restrict__ dinv,
                                                   const float2* __restrict__ gin,
                                                   const float* __restrict__ b3,
                                                   const float* __restrict__ Wc,
                                                   const float* __restrict__ bc,
                                                   float* __restrict__ out,
                                                   float2* __restrict__ hout, int n) {
    __shared__ float acc[FRNG * 3];
    int t = threadIdx.x, b = blockIdx.x;
    for (int i = t; i < FRNG * 3; i += FAB) acc[i] = 0.0f;
    __syncthreads();
    int s0 = b * FCAP;
    int s1 = cursor[b * 16]; if (s1 > s0 + FCAP) s1 = s0 + FCAP;
    int cnt = s1 - s0;
    const int4* cp = (const int4*)(csrp + s0);
    int ng = cnt >> 2;
    for (int g = t; g < ng; g += FAB) {
        int4 p = cp[g];
#pragma unroll
        for (int q = 0; q < 4; q++) {
            int pv = (q == 0) ? p.x : (q == 1) ? p.y : (q == 2) ? p.z : p.w;
            float2 gv = gin[pv >> 9];
            int local = pv & 511;
            atomicAdd(&acc[local * 3 + 0], gv.x);
            atomicAdd(&acc[local * 3 + 1], gv.y);
        }
    }
    int rem = s0 + (ng << 2) + t;
    if (rem < s1) {
        int pv = csrp[rem];
        float2 gv = gin[pv >> 9];
        int local = pv & 511;
        atomicAdd(&acc[local * 3 + 0], gv.x);
        atomicAdd(&acc[local * 3 + 1], gv.y);
    }
    __syncthreads();
    int basen = b * FRNG;
    for (int i = t; i < FRNG; i += FAB) {
        int node = basen + i;
        if (node >= n) continue;
        float2 gs = gin[node];
        float dv = dinv[node];
        float t0 = tanhf(dv * (gs.x + acc[i*3+0]) + b3[0]);
        float t1 = tanhf(dv * (gs.y + acc[i*3+1]) + b3[1]);
        hout[node] = make_float2(t0, t1);
        float4* o = (float4*)(out + (size_t)node * 16);
#pragma unroll
        for (int q = 0; q < 4; q++) {
            float4 v;
            v.x = t0*Wc[4*q+0] + t1*Wc[16+4*q+0] + bc[4*q+0];
            v.y = t0*Wc[4*q+1] + t1*Wc[16+4*q+1] + bc[4*q+1];
            v.z = t0*Wc[4*q+2] + t1*Wc[16+4*q+2] + bc[4*q+2];
            v.w = t0*Wc[4*q+3] + t1*Wc[16+4*q+3] + bc[4*q+3];
            o[q] = v;
        }
    }
}

// ---------------- launcher ----------------

extern "C" void kernel_launch(void* const* d_in, const int* in_sizes, int n_in,
                              void* d_out, int out_size, void* d_ws, size_t ws_size,
                              hipStream_t stream) {
    const float* x   = (const float*)d_in[0];
    const float* W1  = (const float*)d_in[1];
    const float* b1  = (const float*)d_in[2];
    const float* W2  = (const float*)d_in[3];
    const float* b2  = (const float*)d_in[4];
    const float* W3  = (const float*)d_in[5];
    const float* b3  = (const float*)d_in[6];
    const float* Wc  = (const float*)d_in[7];
    const float* bc  = (const float*)d_in[8];
    const int* eidx  = (const int*)d_in[9];

    const int n = in_sizes[0] / 128;   // 200000
    const int e = in_sizes[9] / 2;     // 6400000
    const int* src = eidx;
    const int* dst = eidx + e;

    float* out_c = (float*)d_out;                   // [n,16]
    float* out_h = (float*)d_out + 16 * (size_t)n;  // [n,2]

    size_t nP = ((size_t)n + 3) & ~(size_t)3;

    // 2-D fast-path workspace layout
    size_t szA = (size_t)NRD_MAX * SL * RNGD * 4;   // max(pass1 buf, pdeg, partials)
    int* regA    = (int*)d_ws;
    int* csrp2   = regA + szA;
    int* cur1    = csrp2 + (size_t)NRD_MAX * NS_MAX * CAP2;
    int* cur2    = cur1 + NRD_MAX * 16;
    float* dinv2 = (float*)(cur2 + NRD_MAX * NS_MAX * 16);
    float* g1    = dinv2 + nP;
    float* g2    = g1 + 4 * nP;
    float* g3    = g2 + 4 * nP;
    size_t need2 = (size_t)((char*)(g3 + 2 * nP) - (char*)d_ws);

    int nrd = (n + RNGD - 1) >> RBITS;
    int ns  = (n + SW - 1) >> SBITS;
    bool ok_cap1 = (long long)e * RNGD <= (long long)(CAP1 - 2048) * n;
    double mean2 = (double)e * RNGD * SW / ((double)n * (double)n);
    bool ok_cap2 = mean2 <= (double)(CAP2 - 192);
    bool fast2 = (ws_size >= need2) && (n <= NRD_MAX * RNGD) && (n >= (1 << 15)) &&
                 ok_cap1 && ok_cap2 && (n < (1 << 18));

    if (fast2) {
        int* buf1  = regA;              // pass1 output (dead after pass2)
        int* pdeg  = regA;              // degree partials (dead after mergedeg)
        float* part = (float*)regA;     // aggregation partials

        k_initcur2d<<<(NRD_MAX * NS_MAX + 255) / 256, 256, 0, stream>>>(cur1, cur2);
        k_pass1<<<(e + EPB1 - 1) / EPB1, PB, 0, stream>>>(src, dst, cur1, buf1, e, nrd);
        k_pass2<<<nrd * 16, PB, 0, stream>>>(buf1, cur1, cur2, csrp2, ns);
        k_bdeg2<<<nrd * SL, PB, 0, stream>>>(csrp2, cur2, pdeg, ns);
        k_mergedeg<<<(n + 255) / 256, 256, 0, stream>>>(pdeg, dinv2, n);
        k_linear1<<<(n + 3) / 4, 256, 0, stream>>>(x, W1, dinv2, (float4*)g1, n);
        k_bagg4<<<nrd * SL, PB, 0, stream>>>(csrp2, cur2, (const float4*)g1, part, ns);
        k_merge44<<<(n + 255) / 256, 256, 0, stream>>>(part, (const float4*)g1, dinv2,
                                                       (float4*)g2, W2, b1, n);
        k_bagg4<<<nrd * SL, PB, 0, stream>>>(csrp2, cur2, (const float4*)g2, part, ns);
        k_merge42<<<(n + 255) / 256, 256, 0, stream>>>(part, (const float4*)g2, dinv2,
                                                       (float2*)g3, W3, b2, n);
        k_bagg2<<<nrd * SL, PB, 0, stream>>>(csrp2, cur2, (const float2*)g3, part, ns);
        k_merge2out<<<(n + 255) / 256, 256, 0, stream>>>(part, (const float2*)g3, dinv2,
                                                         b3, Wc, bc, out_c, (float2*)out_h, n);
    } else {
        // fallback: round-5 proven 1-D path (~46MB ws)
        int* csrp    = (int*)d_ws;
        int* cursor  = csrp + (size_t)FNR * FCAP;
        float* dinv  = (float*)(cursor + FNR * 16);
        float* fg1   = dinv + nP;
        float* fg2   = fg1 + 4 * nP;
        float* fg3   = fg2 + 4 * nP;

        const int nbE = (e + FEPB - 1) / FEPB;
        kf_initcur<<<(FNR + 255) / 256, 256, 0, stream>>>(cursor);
        kf_build<<<nbE, FHB, 0, stream>>>(src, dst, cursor, csrp, e);
        kf_bdeg<<<FNR, FAB, 0, stream>>>(csrp, cursor, dinv, n);
        k_linear1<<<(n + 3) / 4, 256, 0, stream>>>(x, W1, dinv, (float4*)fg1, n);
        kf_bagg44<<<FNR, FAB, 0, stream>>>(csrp, cursor, dinv, (const float4*)fg1,
                                           (float4*)fg2, W2, b1, n);
        kf_bagg42<<<FNR, FAB, 0, stream>>>(csrp, cursor, dinv, (const float4*)fg2,
                                           (float2*)fg3, W3, b2, n);
        kf_bagg2out<<<FNR, FAB, 0, stream>>>(csrp, cursor, dinv, (const float2*)fg3,
                                             b3, Wc, bc, out_c, (float2*)out_h, n);
    }
}